// Round 5
// baseline (3763.350 us; speedup 1.0000x reference)
//
#include <hip/hip_runtime.h>
#include <stdint.h>
#include <stddef.h>

// Persistent 2-layer LSTM, V5: 512-thread blocks (16 blocks/cluster, halved
// all-to-all amplification), LDS-shared slab staging, split-flag early release
// (h1+flagA before layer-2 pickup), bias folded into acc init, wave-0 poll.
// B=128,T=512,D=128,H=512. 8 clusters x 16 blocks; block owns 32 h-cols of
// both layers; weights register-resident; 8 waves = 2 col-groups x 4 K-quarters.

typedef __attribute__((ext_vector_type(8))) short short8;
typedef __attribute__((ext_vector_type(4))) float f32x4;
typedef unsigned long long u64;

#define DEV static __device__ __forceinline__
#define SCOPE_AGENT __HIP_MEMORY_SCOPE_AGENT

constexpr int TSEQ = 512;
constexpr int DIN  = 128;
constexpr int HDIM = 512;
constexpr int NCL  = 8;    // clusters (bid&7 -> XCD heuristic; perf-only)
constexpr int BB   = 16;   // batch rows per cluster
constexpr int NJ   = 16;   // blocks per cluster
constexpr int COLS = 32;   // h-cols per block

DEV unsigned short f2bf(float f) {
  unsigned u = __float_as_uint(f);
  u += 0x7fffu + ((u >> 16) & 1u);   // RNE
  return (unsigned short)(u >> 16);
}
DEV short8 pack8(float4 a, float4 b) {
  short8 r;
  r[0] = (short)f2bf(a.x); r[1] = (short)f2bf(a.y);
  r[2] = (short)f2bf(a.z); r[3] = (short)f2bf(a.w);
  r[4] = (short)f2bf(b.x); r[5] = (short)f2bf(b.y);
  r[6] = (short)f2bf(b.z); r[7] = (short)f2bf(b.w);
  return r;
}
DEV short8 mk8(u64 lo, u64 hi) {
  union { u64 q[2]; short8 v; } u;
  u.q[0] = lo; u.q[1] = hi; return u.v;
}
DEV f32x4 mfma16(short8 a, short8 b, f32x4 c) {
  return __builtin_amdgcn_mfma_f32_16x16x32_bf16(a, b, c, 0, 0, 0);
}
DEV float sigf(float v) { return 1.f / (1.f + __expf(-v)); }
DEV float tanh_(float v) {
  v = fminf(20.f, fmaxf(-20.f, v));
  float e = __expf(2.f * v);
  return (e - 1.f) / (e + 1.f);
}

__global__ void zero_ws(unsigned* p, int n) {
  int i = blockIdx.x * 256 + threadIdx.x;
  if (i < n)
    __hip_atomic_store(p + i, 0u, __ATOMIC_RELAXED, SCOPE_AGENT);
}

// LDS slab swizzle on short-index: byte ^ ((row&15)<<4)
#define SWZ(row, idx) ((idx) ^ (((row) & 15) << 3))
// reduction layout: [cg(2)][kq(4)][m(16)][n(66 padded)]
#define REDI(cg, q, m, n) ((cg) * 4224 + ((q) * 16 + (m)) * 66 + (n))

__global__ __launch_bounds__(512, 2) void lstm_persist(
    const float* __restrict__ x,
    const float* __restrict__ Wih1, const float* __restrict__ Whh1,
    const float* __restrict__ bih1, const float* __restrict__ bhh1,
    const float* __restrict__ Wih2, const float* __restrict__ Whh2,
    const float* __restrict__ bih2, const float* __restrict__ bhh2,
    float* __restrict__ out,
    unsigned short* __restrict__ buf1,   // [2][NCL][BB][HDIM] bf16 (h1/out1)
    unsigned short* __restrict__ buf2,   // [2][NCL][BB][HDIM] bf16 (h2)
    unsigned* __restrict__ flags)        // [NCL][2][16]: A then B
{
  __shared__ short xs [16 * DIN];    // 4KB  x_t slab (bf16, swizzled)
  __shared__ short h1s[16 * HDIM];   // 16KB h1_{t-1} slab
  __shared__ short h2s[16 * HDIM];   // 16KB h2_{t-2} slab
  __shared__ float red1[2 * 4224];   // 33.8KB
  __shared__ float red2[2 * 4224];   // 33.8KB

  const int tid  = threadIdx.x;
  const int lane = tid & 63;
  const int lm   = lane & 15;   // A row (batch row) / C col index
  const int lq   = lane >> 4;   // k-octet / C row group
  const int w    = tid >> 6;    // wave 0..7
  const int cg   = w & 1;       // col-group (16 cols each)
  const int kq   = w >> 1;      // K-quarter

  const int bid     = blockIdx.x;
  const int cluster = bid & 7;
  const int j       = bid >> 3;       // 0..15 block within cluster
  const int cb      = cluster * BB;   // global batch base

  // ---- persistent register weights: B-fragments, col = cg*16 + lm ----
  short8 wf1[4][5];   // layer1: K=640 -> 20 K-steps, 5 per K-quarter, x4 gates
  short8 wf2[4][8];   // layer2: K=1024 -> 32 K-steps, 8 per K-quarter, x4 gates
  float b1[4], b2[4];
  #pragma unroll
  for (int g = 0; g < 4; ++g) {
    const int gr = g * HDIM + j * COLS + cg * 16 + lm;
    #pragma unroll
    for (int sl = 0; sl < 5; ++sl) {
      const int k0 = (kq * 5 + sl) * 32 + 8 * lq;          // 0..639
      const float* src = (k0 < DIN) ? (Wih1 + (size_t)gr * DIN + k0)
                                    : (Whh1 + (size_t)gr * HDIM + (k0 - DIN));
      wf1[g][sl] = pack8(*(const float4*)src, *(const float4*)(src + 4));
    }
    #pragma unroll
    for (int sl = 0; sl < 8; ++sl) {
      const int k0 = (kq * 8 + sl) * 32 + 8 * lq;          // 0..1023
      const float* src = (k0 < HDIM) ? (Wih2 + (size_t)gr * HDIM + k0)
                                     : (Whh2 + (size_t)gr * HDIM + (k0 - HDIM));
      wf2[g][sl] = pack8(*(const float4*)src, *(const float4*)(src + 4));
    }
    b1[g] = (kq == 0) ? (bih1[gr] + bhh1[gr]) : 0.f;
    b2[g] = (kq == 0) ? (bih2[gr] + bhh2[gr]) : 0.f;
  }

  // pickup: thread = (batch row pm, col pnn); owns c1,c2 across all steps
  const int pm = tid >> 5, pnn = tid & 31;
  const int pcg = pnn >> 4, pci = pnn & 15;
  float c1 = 0.f, c2 = 0.f;

  for (int it = 0; it <= TSEQ; ++it) {
    const bool l1 = (it < TSEQ);
    const bool l2 = (it >= 1);

    // ---- x pre-load to regs (read-only input; overlaps the poll) ----
    float4 xa, xb;
    const int xrow = tid >> 4, xkc = tid & 15;
    if (tid < 256 && l1) {
      const float* xp = x + ((size_t)(cb + xrow) * TSEQ + it) * DIN + xkc * 8;
      xa = *(const float4*)xp; xb = *(const float4*)(xp + 4);
    }

    // ---- barrier: wave 0 polls flagsA>=it (h1) and flagsB>=it-1 (h2) ----
    if (it > 0 && w == 0) {
      const unsigned* fl = flags + cluster * 32 + (lane & 31);
      const unsigned tgt = ((lane & 31) < NJ) ? (unsigned)it : (unsigned)(it - 1);
      while (true) {
        unsigned v = __hip_atomic_load(fl, __ATOMIC_RELAXED, SCOPE_AGENT);
        if (__all((int)(v >= tgt))) break;
        __builtin_amdgcn_s_sleep(1);
      }
    }
    __syncthreads();

    // ---- stage slabs into swizzled LDS (shared by all 8 waves) ----
    if (tid < 256 && l1)
      *(short8*)(&xs[SWZ(xrow, xrow * DIN + xkc * 8)]) = pack8(xa, xb);
    {
      const unsigned short* h1r =
          buf1 + (size_t)(((it + 1) & 1) * NCL + cluster) * BB * HDIM;
      const unsigned short* h2r =
          buf2 + (size_t)((it & 1) * NCL + cluster) * BB * HDIM;
      const int row = tid >> 5, col0 = (tid & 31) * 16;
      const u64* s1p = (const u64*)(h1r + (size_t)row * HDIM + col0);
      const u64* s2p = (const u64*)(h2r + (size_t)row * HDIM + col0);
      u64 q0 = __hip_atomic_load(s1p,     __ATOMIC_RELAXED, SCOPE_AGENT);
      u64 q1 = __hip_atomic_load(s1p + 1, __ATOMIC_RELAXED, SCOPE_AGENT);
      u64 q2 = __hip_atomic_load(s1p + 2, __ATOMIC_RELAXED, SCOPE_AGENT);
      u64 q3 = __hip_atomic_load(s1p + 3, __ATOMIC_RELAXED, SCOPE_AGENT);
      u64 r0 = __hip_atomic_load(s2p,     __ATOMIC_RELAXED, SCOPE_AGENT);
      u64 r1 = __hip_atomic_load(s2p + 1, __ATOMIC_RELAXED, SCOPE_AGENT);
      u64 r2 = __hip_atomic_load(s2p + 2, __ATOMIC_RELAXED, SCOPE_AGENT);
      u64 r3 = __hip_atomic_load(s2p + 3, __ATOMIC_RELAXED, SCOPE_AGENT);
      *(short8*)(&h1s[SWZ(row, row * HDIM + col0)])     = mk8(q0, q1);
      *(short8*)(&h1s[SWZ(row, row * HDIM + col0 + 8)]) = mk8(q2, q3);
      *(short8*)(&h2s[SWZ(row, row * HDIM + col0)])     = mk8(r0, r1);
      *(short8*)(&h2s[SWZ(row, row * HDIM + col0 + 8)]) = mk8(r2, r3);
    }
    __syncthreads();

    // ---- layer-1 MFMA (acc1 retired to LDS before acc2 lives) ----
    if (l1) {
      f32x4 acc1[4];
      #pragma unroll
      for (int g = 0; g < 4; ++g)
        acc1[g] = f32x4{b1[g], b1[g], b1[g], b1[g]};
      #pragma unroll
      for (int sl = 0; sl < 5; ++sl) {
        const int s = kq * 5 + sl;       // K = [x(4) | h1(16)] K-steps
        short8 a;
        if (s < 4)   // only kq==0
          a = *(const short8*)(&xs[SWZ(lm, lm * DIN + s * 32 + 8 * lq)]);
        else
          a = *(const short8*)(&h1s[SWZ(lm, lm * HDIM + (s - 4) * 32 + 8 * lq)]);
        #pragma unroll
        for (int g = 0; g < 4; ++g) acc1[g] = mfma16(a, wf1[g][sl], acc1[g]);
      }
      #pragma unroll
      for (int g = 0; g < 4; ++g)
        #pragma unroll
        for (int r = 0; r < 4; ++r)
          red1[REDI(cg, kq, lq * 4 + r, g * 16 + lm)] = acc1[g][r];
    }
    // ---- layer-2 MFMA ----
    if (l2) {
      f32x4 acc2[4];
      #pragma unroll
      for (int g = 0; g < 4; ++g)
        acc2[g] = f32x4{b2[g], b2[g], b2[g], b2[g]};
      #pragma unroll
      for (int sl = 0; sl < 8; ++sl) {
        const int s2 = kq * 8 + sl;      // K = [out1(16) | h2(16)] K-steps
        short8 a;
        if (s2 < 16)
          a = *(const short8*)(&h1s[SWZ(lm, lm * HDIM + s2 * 32 + 8 * lq)]);
        else
          a = *(const short8*)(&h2s[SWZ(lm, lm * HDIM + (s2 - 16) * 32 + 8 * lq)]);
        #pragma unroll
        for (int g = 0; g < 4; ++g) acc2[g] = mfma16(a, wf2[g][sl], acc2[g]);
      }
      #pragma unroll
      for (int g = 0; g < 4; ++g)
        #pragma unroll
        for (int r = 0; r < 4; ++r)
          red2[REDI(cg, kq, lq * 4 + r, g * 16 + lm)] = acc2[g][r];
    }
    __syncthreads();

    // ---- layer-1 pickup + publish + flagA (critical path: release early) ----
    if (l1) {
      float p[4];
      #pragma unroll
      for (int g = 0; g < 4; ++g) {
        float v = 0.f;
        #pragma unroll
        for (int q = 0; q < 4; ++q) v += red1[REDI(pcg, q, pm, g * 16 + pci)];
        p[g] = v;
      }
      const float i_ = sigf(p[0]), f_ = sigf(p[1]);
      const float g_ = tanh_(p[2]), o_ = sigf(p[3]);
      c1 = f_ * c1 + i_ * g_;
      const float h1v = o_ * tanh_(c1);
      unsigned short* wp = buf1 + (size_t)((it & 1) * NCL + cluster) * BB * HDIM;
      __hip_atomic_store(&wp[pm * HDIM + j * COLS + pnn], f2bf(h1v),
                         __ATOMIC_RELAXED, SCOPE_AGENT);
    }
    __syncthreads();   // drain all waves' h1 publishes (vmcnt before s_barrier)
    if (tid == 0 && l1)
      __hip_atomic_store(flags + cluster * 32 + j, (unsigned)(it + 1),
                         __ATOMIC_RELAXED, SCOPE_AGENT);

    // ---- layer-2 pickup + publish + flagB (one step of slack) ----
    if (l2) {
      float p[4];
      #pragma unroll
      for (int g = 0; g < 4; ++g) {
        float v = 0.f;
        #pragma unroll
        for (int q = 0; q < 4; ++q) v += red2[REDI(pcg, q, pm, g * 16 + pci)];
        p[g] = v;
      }
      const float i_ = sigf(p[0]), f_ = sigf(p[1]);
      const float g_ = tanh_(p[2]), o_ = sigf(p[3]);
      c2 = f_ * c2 + i_ * g_;
      const float h2v = o_ * tanh_(c2);
      if (l1) {
        unsigned short* wp =
            buf2 + (size_t)(((it + 1) & 1) * NCL + cluster) * BB * HDIM;
        __hip_atomic_store(&wp[pm * HDIM + j * COLS + pnn], f2bf(h2v),
                           __ATOMIC_RELAXED, SCOPE_AGENT);
      } else {
        const int b = cb + pm;                       // final states (t = 511)
        out[(size_t)b * HDIM + j * COLS + pnn] = h2v;
        out[(size_t)128 * HDIM + (size_t)b * HDIM + j * COLS + pnn] = c2;
      }
    }
    __syncthreads();   // drain h2 publishes
    if (tid == 0 && l1 && l2)
      __hip_atomic_store(flags + cluster * 32 + NJ + j, (unsigned)it,
                         __ATOMIC_RELAXED, SCOPE_AGENT);
  }
}

extern "C" void kernel_launch(void* const* d_in, const int* in_sizes, int n_in,
                              void* d_out, int out_size, void* d_ws, size_t ws_size,
                              hipStream_t stream) {
  const float* x    = (const float*)d_in[0];
  const float* Wih1 = (const float*)d_in[1];
  const float* Whh1 = (const float*)d_in[2];
  const float* bih1 = (const float*)d_in[3];
  const float* bhh1 = (const float*)d_in[4];
  const float* Wih2 = (const float*)d_in[5];
  const float* Whh2 = (const float*)d_in[6];
  const float* bih2 = (const float*)d_in[7];
  const float* bhh2 = (const float*)d_in[8];
  float* out = (float*)d_out;

  const size_t bufElems = (size_t)2 * NCL * BB * HDIM;   // 131072 ushorts each
  unsigned short* buf1 = (unsigned short*)d_ws;
  unsigned short* buf2 = buf1 + bufElems;
  unsigned* flags = (unsigned*)(buf2 + bufElems);

  const int nzero = (int)((bufElems * 2 * 2 + NCL * 32 * 4) / 4);   // u32 words
  zero_ws<<<(nzero + 255) / 256, 256, 0, stream>>>((unsigned*)d_ws, nzero);
  lstm_persist<<<128, 512, 0, stream>>>(x, Wih1, Whh1, bih1, bhh1,
                                        Wih2, Whh2, bih2, bhh2,
                                        out, buf1, buf2, flags);
}

// Round 6
// 1985.890 us; speedup vs baseline: 1.8950x; 1.8950x over previous
//
#include <hip/hip_runtime.h>
#include <stdint.h>
#include <stddef.h>

// Persistent 2-layer LSTM, V6: V3 structure (256-thread blocks, LDS slab
// staging, 208-VGPR register-resident weights) + per-block flag barrier
// (no RMW serialization), split early flag release (h1 before layer-2 tail),
// and a kept-alive LDS pad forcing 1 block/CU (deterministic placement).
// B=128,T=512,D=128,H=512. 8 clusters x 32 blocks; block owns 16 h-cols of
// both layers; 4 waves = 4 K-quarters.

typedef __attribute__((ext_vector_type(8))) short short8;
typedef __attribute__((ext_vector_type(4))) float f32x4;
typedef unsigned long long u64;

#define DEV static __device__ __forceinline__
#define SCOPE_AGENT __HIP_MEMORY_SCOPE_AGENT

constexpr int TSEQ = 512;
constexpr int DIN  = 128;
constexpr int HDIM = 512;
constexpr int NCL  = 8;    // clusters (bid&7 -> XCD heuristic; perf-only)
constexpr int BB   = 16;   // batch rows per cluster
constexpr int NJ   = 32;   // blocks per cluster
constexpr int COLS = 16;   // h-cols per block

DEV unsigned short f2bf(float f) {
  unsigned u = __float_as_uint(f);
  u += 0x7fffu + ((u >> 16) & 1u);   // RNE
  return (unsigned short)(u >> 16);
}
DEV short8 pack8(float4 a, float4 b) {
  short8 r;
  r[0] = (short)f2bf(a.x); r[1] = (short)f2bf(a.y);
  r[2] = (short)f2bf(a.z); r[3] = (short)f2bf(a.w);
  r[4] = (short)f2bf(b.x); r[5] = (short)f2bf(b.y);
  r[6] = (short)f2bf(b.z); r[7] = (short)f2bf(b.w);
  return r;
}
DEV short8 mk8(u64 lo, u64 hi) {
  union { u64 q[2]; short8 v; } u;
  u.q[0] = lo; u.q[1] = hi; return u.v;
}
DEV f32x4 mfma16(short8 a, short8 b, f32x4 c) {
  return __builtin_amdgcn_mfma_f32_16x16x32_bf16(a, b, c, 0, 0, 0);
}
DEV float sigf(float v) { return 1.f / (1.f + __expf(-v)); }
DEV float tanh_(float v) {
  v = fminf(20.f, fmaxf(-20.f, v));
  float e = __expf(2.f * v);
  return (e - 1.f) / (e + 1.f);
}

__global__ void zero_ws(unsigned* p, int n) {
  int i = blockIdx.x * 256 + threadIdx.x;
  if (i < n)
    __hip_atomic_store(p + i, 0u, __ATOMIC_RELAXED, SCOPE_AGENT);
}

// LDS slab swizzle on short-index: byte ^ ((row&15)<<4)
#define SWZ(row, idx) ((idx) ^ (((row) & 15) << 3))

__global__ __launch_bounds__(256, 1) void lstm_persist(
    const float* __restrict__ x,
    const float* __restrict__ Wih1, const float* __restrict__ Whh1,
    const float* __restrict__ bih1, const float* __restrict__ bhh1,
    const float* __restrict__ Wih2, const float* __restrict__ Whh2,
    const float* __restrict__ bih2, const float* __restrict__ bhh2,
    float* __restrict__ out,
    unsigned short* __restrict__ buf1,   // [2][NCL][BB][HDIM] bf16 (h1/out1)
    unsigned short* __restrict__ buf2,   // [2][NCL][BB][HDIM] bf16 (h2)
    unsigned* __restrict__ flags)        // [NCL][64]: A flags 0..31, B flags 32..63
{
  __shared__ short xs [16 * DIN];    // 4KB  x_t slab (bf16, swizzled)
  __shared__ short h1s[16 * HDIM];   // 16KB h1_{t-1} slab
  __shared__ short h2s[16 * HDIM];   // 16KB h2_{t-2} slab
  __shared__ float red1[4 * 16 * 66];
  __shared__ float red2[4 * 16 * 66];
  __shared__ float bias1s[64], bias2s[64];
  __shared__ float occpad[3072];     // 12KB pad -> 83KB total -> 1 block/CU

  const int tid  = threadIdx.x;
  const int lane = tid & 63;
  const int lm   = lane & 15;   // A row (batch row) / C col index
  const int lq   = lane >> 4;   // k-octet / C row group
  const int kq   = tid >> 6;    // wave = K-quarter

  const int bid     = blockIdx.x;
  const int cluster = bid & 7;
  const int j       = bid >> 3;       // 0..31 col-group within cluster
  const int cb      = cluster * BB;   // global batch base

  // keep occpad allocated (rule: write-only LDS gets DCE'd)
  asm volatile("" :: "v"(&occpad[tid & 1023]));

  // ---- persistent register weights: B-fragments, n = lane&15 -> gate row ----
  short8 wf1[4][5];   // layer1: K=640 -> 20 K-steps, 5 per wave, x4 gates
  short8 wf2[4][8];   // layer2: K=1024 -> 32 K-steps, 8 per wave, x4 gates
  #pragma unroll
  for (int g = 0; g < 4; ++g) {
    const int gr = g * HDIM + j * COLS + lm;
    #pragma unroll
    for (int sl = 0; sl < 5; ++sl) {
      const int k0 = (kq * 5 + sl) * 32 + 8 * lq;          // 0..639
      const float* src = (k0 < DIN) ? (Wih1 + (size_t)gr * DIN + k0)
                                    : (Whh1 + (size_t)gr * HDIM + (k0 - DIN));
      wf1[g][sl] = pack8(*(const float4*)src, *(const float4*)(src + 4));
    }
    #pragma unroll
    for (int sl = 0; sl < 8; ++sl) {
      const int k0 = (kq * 8 + sl) * 32 + 8 * lq;          // 0..1023
      const float* src = (k0 < HDIM) ? (Wih2 + (size_t)gr * HDIM + k0)
                                     : (Whh2 + (size_t)gr * HDIM + (k0 - HDIM));
      wf2[g][sl] = pack8(*(const float4*)src, *(const float4*)(src + 4));
    }
  }
  if (tid < 64) {
    const int g = tid >> 4, nn = tid & 15;
    const int gr = g * HDIM + j * COLS + nn;
    bias1s[tid] = bih1[gr] + bhh1[gr];
    bias2s[tid] = bih2[gr] + bhh2[gr];
  }

  // pickup: thread = (batch row pm, col pnn); owns c1,c2 across all steps
  const int pm = tid >> 4, pnn = tid & 15;
  float c1 = 0.f, c2 = 0.f;

  for (int it = 0; it <= TSEQ; ++it) {
    const bool l1 = (it < TSEQ);
    const bool l2 = (it >= 1);

    // ---- stage x_t (peer-independent; issued before the poll) ----
    if (l1) {
      const int row = tid >> 4, kc = tid & 15;
      const float* xp = x + ((size_t)(cb + row) * TSEQ + it) * DIN + kc * 8;
      *(short8*)(&xs[SWZ(row, row * DIN + kc * 8)]) =
          pack8(*(const float4*)xp, *(const float4*)(xp + 4));
    }

    // ---- barrier: wave 0 polls per-block flags (A: h1>=it, B: h2>=it-1) ----
    if (it > 0) {
      if (kq == 0) {
        const unsigned* fl = flags + cluster * 64 + lane;
        const unsigned tgt = (lane < NJ) ? (unsigned)it : (unsigned)(it - 1);
        while (true) {
          unsigned v = __hip_atomic_load(fl, __ATOMIC_RELAXED, SCOPE_AGENT);
          if (__all((int)(v >= tgt))) break;
          __builtin_amdgcn_s_sleep(1);
        }
      }
      __syncthreads();
    }

    // ---- stage h slabs via cache-bypassing loads (shared by 4 waves) ----
    const unsigned short* h1r =
        buf1 + (size_t)(((it + 1) & 1) * NCL + cluster) * BB * HDIM;  // h1_{it-1}
    const unsigned short* h2r =
        buf2 + (size_t)((it & 1) * NCL + cluster) * BB * HDIM;        // h2_{it-2}
    {
      u64 t[8];
      #pragma unroll
      for (int ci = 0; ci < 4; ++ci) {
        const int c = ci * 256 + tid;
        const int row = c >> 6, kc = c & 63;
        const u64* s = (const u64*)(h1r + (size_t)row * HDIM + kc * 8);
        t[2 * ci]     = __hip_atomic_load(s,     __ATOMIC_RELAXED, SCOPE_AGENT);
        t[2 * ci + 1] = __hip_atomic_load(s + 1, __ATOMIC_RELAXED, SCOPE_AGENT);
      }
      #pragma unroll
      for (int ci = 0; ci < 4; ++ci) {
        const int c = ci * 256 + tid;
        const int row = c >> 6, kc = c & 63;
        u64* d = (u64*)&h1s[SWZ(row, row * HDIM + kc * 8)];
        d[0] = t[2 * ci]; d[1] = t[2 * ci + 1];
      }
      #pragma unroll
      for (int ci = 0; ci < 4; ++ci) {
        const int c = ci * 256 + tid;
        const int row = c >> 6, kc = c & 63;
        const u64* s = (const u64*)(h2r + (size_t)row * HDIM + kc * 8);
        t[2 * ci]     = __hip_atomic_load(s,     __ATOMIC_RELAXED, SCOPE_AGENT);
        t[2 * ci + 1] = __hip_atomic_load(s + 1, __ATOMIC_RELAXED, SCOPE_AGENT);
      }
      #pragma unroll
      for (int ci = 0; ci < 4; ++ci) {
        const int c = ci * 256 + tid;
        const int row = c >> 6, kc = c & 63;
        u64* d = (u64*)&h2s[SWZ(row, row * HDIM + kc * 8)];
        d[0] = t[2 * ci]; d[1] = t[2 * ci + 1];
      }
    }
    __syncthreads();

    // ---- MFMA: wave kq does its K-quarter, all 4 gate N-tiles ----
    f32x4 z = {0.f, 0.f, 0.f, 0.f};
    f32x4 acc1[4] = {z, z, z, z};
    f32x4 acc2[4] = {z, z, z, z};
    if (l1) {
      #pragma unroll
      for (int sl = 0; sl < 5; ++sl) {
        const int s = kq * 5 + sl;       // K = [x(4) | h1(16)] K-steps
        short8 a;
        if (s < 4)   // only kq==0
          a = *(const short8*)(&xs[SWZ(lm, lm * DIN + s * 32 + 8 * lq)]);
        else
          a = *(const short8*)(&h1s[SWZ(lm, lm * HDIM + (s - 4) * 32 + 8 * lq)]);
        #pragma unroll
        for (int g = 0; g < 4; ++g) acc1[g] = mfma16(a, wf1[g][sl], acc1[g]);
      }
    }
    if (l2) {
      #pragma unroll
      for (int sl = 0; sl < 8; ++sl) {
        const int s2 = kq * 8 + sl;      // K = [out1(16) | h2(16)] K-steps
        short8 a;
        if (s2 < 16)
          a = *(const short8*)(&h1s[SWZ(lm, lm * HDIM + s2 * 32 + 8 * lq)]);
        else
          a = *(const short8*)(&h2s[SWZ(lm, lm * HDIM + (s2 - 16) * 32 + 8 * lq)]);
        #pragma unroll
        for (int g = 0; g < 4; ++g) acc2[g] = mfma16(a, wf2[g][sl], acc2[g]);
      }
    }
    // C layout: col = lane&15 (gate row), row = lq*4+r (batch row)
    if (l1) {
      #pragma unroll
      for (int g = 0; g < 4; ++g)
        #pragma unroll
        for (int r = 0; r < 4; ++r)
          red1[(kq * 16 + lq * 4 + r) * 66 + g * 16 + lm] = acc1[g][r];
    }
    if (l2) {
      #pragma unroll
      for (int g = 0; g < 4; ++g)
        #pragma unroll
        for (int r = 0; r < 4; ++r)
          red2[(kq * 16 + lq * 4 + r) * 66 + g * 16 + lm] = acc2[g][r];
    }
    __syncthreads();

    // ---- layer-1 pickup + publish + flagA (h1 recurrence critical path) ----
    if (l1) {
      float p[4];
      #pragma unroll
      for (int g = 0; g < 4; ++g) {
        float v = bias1s[g * 16 + pnn];
        #pragma unroll
        for (int q = 0; q < 4; ++q) v += red1[(q * 16 + pm) * 66 + g * 16 + pnn];
        p[g] = v;
      }
      const float i_ = sigf(p[0]), f_ = sigf(p[1]);
      const float g_ = tanh_(p[2]), o_ = sigf(p[3]);
      c1 = f_ * c1 + i_ * g_;
      const float h1v = o_ * tanh_(c1);
      unsigned short* wp = buf1 + (size_t)((it & 1) * NCL + cluster) * BB * HDIM;
      __hip_atomic_store(&wp[pm * HDIM + j * COLS + pnn], f2bf(h1v),
                         __ATOMIC_RELAXED, SCOPE_AGENT);
    }
    __syncthreads();   // drains vmcnt: all h1 publishes complete
    if (tid == 0 && l1)
      __hip_atomic_store(flags + cluster * 64 + j, (unsigned)(it + 1),
                         __ATOMIC_RELAXED, SCOPE_AGENT);

    // ---- layer-2 pickup + publish + flagB (one step of slack) ----
    if (l2) {
      float p[4];
      #pragma unroll
      for (int g = 0; g < 4; ++g) {
        float v = bias2s[g * 16 + pnn];
        #pragma unroll
        for (int q = 0; q < 4; ++q) v += red2[(q * 16 + pm) * 66 + g * 16 + pnn];
        p[g] = v;
      }
      const float i_ = sigf(p[0]), f_ = sigf(p[1]);
      const float g_ = tanh_(p[2]), o_ = sigf(p[3]);
      c2 = f_ * c2 + i_ * g_;
      const float h2v = o_ * tanh_(c2);
      if (l1) {
        unsigned short* wp =
            buf2 + (size_t)(((it + 1) & 1) * NCL + cluster) * BB * HDIM;
        __hip_atomic_store(&wp[pm * HDIM + j * COLS + pnn], f2bf(h2v),
                           __ATOMIC_RELAXED, SCOPE_AGENT);
      } else {
        const int b = cb + pm;                       // final states (t = 511)
        out[(size_t)b * HDIM + j * COLS + pnn] = h2v;
        out[(size_t)128 * HDIM + (size_t)b * HDIM + j * COLS + pnn] = c2;
      }
    }
    __syncthreads();   // drains vmcnt: all h2 publishes complete
    if (tid == 0 && l1 && l2)
      __hip_atomic_store(flags + cluster * 64 + NJ + j, (unsigned)it,
                         __ATOMIC_RELAXED, SCOPE_AGENT);
  }
}

extern "C" void kernel_launch(void* const* d_in, const int* in_sizes, int n_in,
                              void* d_out, int out_size, void* d_ws, size_t ws_size,
                              hipStream_t stream) {
  const float* x    = (const float*)d_in[0];
  const float* Wih1 = (const float*)d_in[1];
  const float* Whh1 = (const float*)d_in[2];
  const float* bih1 = (const float*)d_in[3];
  const float* bhh1 = (const float*)d_in[4];
  const float* Wih2 = (const float*)d_in[5];
  const float* Whh2 = (const float*)d_in[6];
  const float* bih2 = (const float*)d_in[7];
  const float* bhh2 = (const float*)d_in[8];
  float* out = (float*)d_out;

  const size_t bufElems = (size_t)2 * NCL * BB * HDIM;   // 131072 ushorts each
  unsigned short* buf1 = (unsigned short*)d_ws;
  unsigned short* buf2 = buf1 + bufElems;
  unsigned* flags = (unsigned*)(buf2 + bufElems);

  const int nzero = (int)((bufElems * 2 * 2 + NCL * 64 * 4) / 4);   // u32 words
  zero_ws<<<(nzero + 255) / 256, 256, 0, stream>>>((unsigned*)d_ws, nzero);
  lstm_persist<<<256, 256, 0, stream>>>(x, Wih1, Whh1, bih1, bhh1,
                                        Wih2, Whh2, bih2, bhh2,
                                        out, buf1, buf2, flags);
}